// Round 12
// baseline (319.672 us; speedup 1.0000x reference)
//
#include <hip/hip_runtime.h>
#include <hip/hip_fp16.h>

// 3-layer gather-GEMM GNN (N=262144, K=8, 16->128->128->16), f16 MFMA.
// Round 24: layer0 latency-chain cuts + dispatch elimination (layer1p and
// reduce remain frozen at their r19 forms).
//   * invd quad-split: threads with equal (wave,lmod) share rows; quad q
//     now computes only neighbors {2q,2q+1} (12 pos loads + 4 sqrt chains
//     per thread, was ~54/16) and all 8 values are exchanged via a 2KB LDS
//     buffer under the existing barrier. Same f32 expression per edge,
//     computed once -> bit-identical.
//   * W0 staged into LDS directly from global f32 (8 strided scalar loads
//     per 16B granule; W0 = 64KB, L2-hot; (_Float16) = same RTN cvt) ->
//     W0f scratch and its producer pass die.
//   * W1f/W2s shuffles folded into layer0's grid as tail blocks 2048..2623
//     (consumed only by the NEXT dispatch -> race-free). prep_all dispatch
//     deleted: 4 dispatches total.
//
// Workspace: ws = h1 (64 MiB) + P (64 MiB) = 128 MiB exactly. invd/W1f/W2s
// live in d_out scratch; invd is d2d-copied into dead h1 before the reduce
// (which overwrites d_out).

typedef _Float16 f16x8 __attribute__((ext_vector_type(8)));
typedef float f32x4 __attribute__((ext_vector_type(4)));

#define NNODES 262144

// ------- L0 (+fused prep): F_IN=16, F_OUT=128, 128 rows/block -------
// Blocks [0,2048): layer0 rows. Blocks [2048,2624): W1f/W2s shuffles.
__global__ __launch_bounds__(256) void layer0_kernel(
    const float* __restrict__ h, const float* __restrict__ pos,
    const int* __restrict__ nbr,
    const float* __restrict__ W0, const float* __restrict__ W1,
    const float* __restrict__ W2, const float* __restrict__ bias,
    __half* __restrict__ invd, __half* __restrict__ W1f,
    __half* __restrict__ W2f, __half* __restrict__ outp) {
    __shared__ __align__(16) __half Bs[16384];      // 32 KB: W0 frags, then h1 bounce
    __shared__ __align__(16) __half exch[2][64][8]; // 2 KB invd exchange

    const int b = blockIdx.x;
    const int tid = threadIdx.x;

    if (b >= 2048) {  // ---- fused weight-shuffle tail (feeds layer1p) ----
        const int bb = b - 2048;
        if (bb < 512) {                  // W1f: KT=1024, FO=128 (131072 elems)
            int e = bb * 256 + tid;
            int j = e & 7;
            int lane = (e >> 3) & 63;
            int rest = e >> 9;
            int tt = rest % 8;
            int s = rest / 8;
            int k = s * 32 + (lane >> 4) * 8 + j;
            int n = tt * 16 + (lane & 15);
            W1f[e] = __float2half(W1[k * 128 + n]);
        } else {                         // W2 stacked shuffle (16384 elems)
            int e = (bb - 512) * 256 + tid;
            int j = e & 7;
            int lane = (e >> 3) & 63;
            int rest = e >> 9;
            int tt = rest % 8;
            int s = rest / 8;
            int k = s * 32 + (lane >> 4) * 8 + j;
            W2f[e] = __float2half(W2[(size_t)(tt * 128 + k) * 16 + (lane & 15)]);
        }
        return;
    }

    const int wave = tid >> 6;
    const int lane = tid & 63;
    const int quad = lane >> 4;
    const int lmod = lane & 15;
    const int mbase = b * 128 + wave * 16 + lmod;
    const int grp = wave * 16 + lmod;   // exchange group (quad-independent)

    // Stage W0 fragments into LDS directly from global f32:
    // Bs[G*8+j] = (half)W0[(s*32+(ln>>4)*8+j)*128 + t*16+(ln&15)],
    // G = i*256+tid, s=G>>9, t=(G>>6)&7, ln=G&63.  (_Float16) = RTN cvt.
    {
#pragma unroll
        for (int i = 0; i < 8; ++i) {
            const int G = i * 256 + tid;
            const int s = G >> 9;
            const int t = (G >> 6) & 7;
            const int ln = G & 63;
            const float* wp = W0 + (size_t)(s * 32 + (ln >> 4) * 8) * 128 + t * 16 + (ln & 15);
            f16x8 v;
#pragma unroll
            for (int j = 0; j < 8; ++j) v[j] = (_Float16)wp[j * 128];
            *(f16x8*)(Bs + (size_t)G * 8) = v;
        }
    }

    int idx[2][8];
#pragma unroll
    for (int mt = 0; mt < 2; ++mt) {
        const int m = mbase + mt * 64;
        const int4* nrow = (const int4*)(nbr + (size_t)m * 8);
        const int4 iA = nrow[0];
        const int4 iB = nrow[1];
        idx[mt][0] = iA.x; idx[mt][1] = iA.y; idx[mt][2] = iA.z; idx[mt][3] = iA.w;
        idx[mt][4] = iB.x; idx[mt][5] = iB.y; idx[mt][6] = iB.z; idx[mt][7] = iB.w;
    }

    // invd, quad-split: this quad computes neighbors {2q, 2q+1} only;
    // identical f32 math as before -> bit-identical values.
#pragma unroll
    for (int mt = 0; mt < 2; ++mt) {
        const int m = mbase + mt * 64;
        const float px = pos[m * 3 + 0];
        const float py = pos[m * 3 + 1];
        const float pz = pos[m * 3 + 2];
#pragma unroll
        for (int kk = 0; kk < 2; ++kk) {
            const int k = quad * 2 + kk;
            const int n = idx[mt][k];
            const float dx = px - pos[n * 3 + 0];
            const float dy = py - pos[n * 3 + 1];
            const float dz = pz - pos[n * 3 + 2];
            float d = sqrtf(dx * dx + dy * dy + dz * dz);
            if (d == 0.0f) d = 0.5f;     // reference: where(dist==0, 0.5, dist)
            exch[mt][grp][k] = (_Float16)((1.0f / d) * 0.00390625f);  // prescale 1/256
        }
    }

    f32x4 acc[2][8];
#pragma unroll
    for (int mt = 0; mt < 2; ++mt)
#pragma unroll
        for (int t = 0; t < 8; ++t) acc[mt][t] = f32x4{0.f, 0.f, 0.f, 0.f};

    __syncthreads();  // Bs staging + exch writes complete

    f16x8 invr[2];
#pragma unroll
    for (int mt = 0; mt < 2; ++mt) {
        invr[mt] = *(const f16x8*)&exch[mt][grp][0];
        if (quad == 0) *(f16x8*)(invd + (size_t)(mbase + mt * 64) * 8) = invr[mt];
    }

#pragma unroll
    for (int s = 0; s < 4; ++s) {
        const int nb = 2 * s + (quad >> 1);
        f16x8 as[2];
#pragma unroll
        for (int mt = 0; mt < 2; ++mt) {
            const float* hp = h + (size_t)idx[mt][nb] * 16 + (quad & 1) * 8;
            const float4 f0 = *(const float4*)(hp);
            const float4 f1 = *(const float4*)(hp + 4);
            f16x8 av;
            av[0] = (_Float16)f0.x; av[1] = (_Float16)f0.y;
            av[2] = (_Float16)f0.z; av[3] = (_Float16)f0.w;
            av[4] = (_Float16)f1.x; av[5] = (_Float16)f1.y;
            av[6] = (_Float16)f1.z; av[7] = (_Float16)f1.w;
            as[mt] = av * invr[mt][nb];
        }
#pragma unroll
        for (int t = 0; t < 8; ++t) {
            f16x8 bb = *(const f16x8*)(Bs + ((size_t)(s * 8 + t) * 64 + lane) * 8);
#pragma unroll
            for (int mt = 0; mt < 2; ++mt)
                acc[mt][t] = __builtin_amdgcn_mfma_f32_16x16x32_f16(as[mt], bb, acc[mt][t], 0, 0, 0);
        }
    }

    // ---- Epilogue: bounce 128x128 f16 tile through Bs, coalesced dump ----
    __syncthreads();  // all Bs (weights) reads complete before overwrite
#pragma unroll
    for (int mt = 0; mt < 2; ++mt) {
#pragma unroll
        for (int t = 0; t < 8; ++t) {
            const int col = t * 16 + lmod;
            const float bv = bias[col];
#pragma unroll
            for (int rr = 0; rr < 4; ++rr) {
                const int lrow = mt * 64 + wave * 16 + quad * 4 + rr;
                float v = acc[mt][t][rr] * 256.0f + bv;
                Bs[lrow * 128 + col] = __float2half(v);
            }
        }
    }
    __syncthreads();
    {
        const int lrow = tid >> 1;                 // 0..127
        const int cb = (tid & 1) * 64;             // col base 0 or 64
        __half* gdst = outp + (size_t)(b * 128 + lrow) * 128 + cb;
        const __half* lsrc = Bs + lrow * 128 + cb;
#pragma unroll
        for (int j = 0; j < 8; ++j)
            *(f16x8*)(gdst + j * 8) = *(const f16x8*)(lsrc + j * 8);
    }
}

// ------- L1+P: F_IN=128, F_OUT=128, 64 rows/block, fused P projection -------
// 512 threads / 8 waves; wave owns one col-tile t = wave.  (r19 form, frozen.)
// LDS: seg-major + XOR swizzle, 16B granules: off16(seg,row) =
//   seg*64 + (row & ~15) + ((row ^ seg) & 15)   -> spans [0, 1024) granules.
__device__ __forceinline__ int off16(int seg, int row) {
    return seg * 64 + (row & ~15) + ((row ^ seg) & 15);
}

__global__ __launch_bounds__(512, 4) void layer1p_kernel(
    const __half* __restrict__ hprev, const __half* __restrict__ invd,
    const int* __restrict__ nbr, const __half* __restrict__ Wf,
    const __half* __restrict__ Wf2s, const float* __restrict__ bias,
    __half* __restrict__ Pout) {
    __shared__ __align__(16) __half As[2][8192];  // 2 x 1024 granules x 16B = 32 KB

    const int tid = threadIdx.x;
    const int wave = tid >> 6;          // 0..7: this wave's col-tile
    const int lane = tid & 63;
    const int quad = lane >> 4;
    const int lmod = lane & 15;
    const int rowblk = blockIdx.x * 64;
    const int seg = lmod;               // staging: this thread's 16B segment

    // Staging rows: r0 = wave*4 + quad (0..31) and r0+32; seg = lmod.
    const int r0 = wave * 4 + quad;
    const int* nbp = nbr + (size_t)(rowblk + r0) * 8;      // +256 ints = row r0+32
    const __half* ivp = invd + (size_t)(rowblk + r0) * 8;  // +256 halves = row r0+32

    const int soff0 = off16(seg, r0) * 8;        // halves
    const int soff1 = off16(seg, r0 + 32) * 8;

    // Fragment-read offsets (halves): off16(ks*4+quad, m*16+lmod)*8 =
    // roff4[ks] + m*128.
    int roff4[4];
#pragma unroll
    for (int ks = 0; ks < 4; ++ks) {
        const int sg = ks * 4 + quad;
        roff4[ks] = (sg * 64 + ((lmod ^ sg) & 15)) * 8;
    }

    // This wave's B fragments: col-tile t = wave; k-step s at +s*4096 halves.
    const __half* WfB = Wf + ((size_t)wave * 64 + lane) * 8;

    // Half-width B ring: phase p = nb*2 + h covers s = 2p, 2p+1.
    f16x8 Bc[2], Bn[2];
#pragma unroll
    for (int ks2 = 0; ks2 < 2; ++ks2)
        Bc[ks2] = *(const f16x8*)(WfB + (size_t)ks2 * 4096);

    // 2-deep gather ring (global->VGPR loads cross barriers); indices JIT.
    f16x8 ga[2][2];
    {
        int id0[2], id1[2];
        id0[0] = nbp[0];   id0[1] = nbp[256];
        ga[0][0] = *(const f16x8*)(hprev + (size_t)id0[0] * 128 + seg * 8);
        ga[0][1] = *(const f16x8*)(hprev + (size_t)id0[1] * 128 + seg * 8);
        id1[0] = nbp[1];   id1[1] = nbp[257];
        ga[1][0] = *(const f16x8*)(hprev + (size_t)id1[0] * 128 + seg * 8);
        ga[1][1] = *(const f16x8*)(hprev + (size_t)id1[1] * 128 + seg * 8);
    }

    // Stage neighbor 0 (scaled) into As[0].
    {
        const _Float16 s0 = *(const _Float16*)(ivp + 0);
        const _Float16 s1 = *(const _Float16*)(ivp + 256);
        *(f16x8*)(&As[0][soff0]) = ga[0][0] * s0;
        *(f16x8*)(&As[0][soff1]) = ga[0][1] * s1;
    }
    __syncthreads();

    f32x4 acc[4];
#pragma unroll
    for (int m = 0; m < 4; ++m) acc[m] = f32x4{0.f, 0.f, 0.f, 0.f};

#pragma unroll
    for (int nb = 0; nb < 8; ++nb) {
        const int cur = nb & 1;
        // JIT indices for neighbor nb+2 (L1-hot), gather into ga[cur]
        // (slot's old data = neighbor nb, already staged).
        if (nb < 6) {
            int idn[2];
            idn[0] = nbp[nb + 2];
            idn[1] = nbp[nb + 258];
            ga[cur][0] = *(const f16x8*)(hprev + (size_t)idn[0] * 128 + seg * 8);
            ga[cur][1] = *(const f16x8*)(hprev + (size_t)idn[1] * 128 + seg * 8);
        }
        // Compute from As[cur]: two B half-phases (ks = h*2 + ks2).
#pragma unroll
        for (int h = 0; h < 2; ++h) {
            const int p = nb * 2 + h;
            if (p < 15) {
#pragma unroll
                for (int ks2 = 0; ks2 < 2; ++ks2)
                    Bn[ks2] = *(const f16x8*)(WfB + (size_t)((p + 1) * 2 + ks2) * 4096);
            }
#pragma unroll
            for (int m = 0; m < 4; ++m) {
#pragma unroll
                for (int ks2 = 0; ks2 < 2; ++ks2) {
                    f16x8 a = *(const f16x8*)(&As[cur][roff4[h * 2 + ks2] + m * 128]);
                    acc[m] = __builtin_amdgcn_mfma_f32_16x16x32_f16(a, Bc[ks2], acc[m], 0, 0, 0);
                }
            }
            Bc[0] = Bn[0];
            Bc[1] = Bn[1];
        }
        // Stage neighbor nb+1 (scaled), then barrier.
        if (nb < 7) {
            const _Float16 s0 = *(const _Float16*)(ivp + nb + 1);
            const _Float16 s1 = *(const _Float16*)(ivp + nb + 257);
            *(f16x8*)(&As[cur ^ 1][soff0]) = ga[(nb + 1) & 1][0] * s0;
            *(f16x8*)(&As[cur ^ 1][soff1]) = ga[(nb + 1) & 1][1] * s1;
            __syncthreads();
        }
    }

    // ---- Fused epilogue: h2 = leaky(acc*256 + b1) -> LDS (swizzled) ----
    // As[0] is free (last read at nb=6's compute, before the last barrier).
    // h2 element (row,col) at granule off16(col>>3, row), half (col&7).
    // Wave writes its 16 cols: col = wave*16 + lmod.
    __half* As0 = &As[0][0];
    {
        const int col = wave * 16 + lmod;
        const float bv = bias[col];
        const int sg = col >> 3;
        const int jj = col & 7;
#pragma unroll
        for (int m = 0; m < 4; ++m) {
#pragma unroll
            for (int rr = 0; rr < 4; ++rr) {
                const int row = m * 16 + quad * 4 + rr;
                float v = acc[m][rr] * 256.0f + bv;
                v = (v >= 0.f) ? v : 0.01f * v;
                As0[off16(sg, row) * 8 + jj] = __float2half(v);
            }
        }
    }
    __syncthreads();

    // ---- P = h2 @ W2s (K=128, 4 k-steps); wave owns col-tile wave ----
    const __half* WfB2 = Wf2s + ((size_t)wave * 64 + lane) * 8;
    f16x8 B2[4];
#pragma unroll
    for (int ks = 0; ks < 4; ++ks)
        B2[ks] = *(const f16x8*)(WfB2 + (size_t)ks * 4096);

    f32x4 acc2[4];
#pragma unroll
    for (int m = 0; m < 4; ++m) acc2[m] = f32x4{0.f, 0.f, 0.f, 0.f};
#pragma unroll
    for (int m = 0; m < 4; ++m) {
#pragma unroll
        for (int ks = 0; ks < 4; ++ks) {
            f16x8 a2 = *(const f16x8*)(&As0[roff4[ks] + m * 128]);
            acc2[m] = __builtin_amdgcn_mfma_f32_16x16x32_f16(a2, B2[ks], acc2[m], 0, 0, 0);
        }
    }

    // ---- write P (fp16, true scale) ----
    {
        const int col = wave * 16 + lmod;
#pragma unroll
        for (int m = 0; m < 4; ++m) {
#pragma unroll
            for (int rr = 0; rr < 4; ++rr) {
                const int grow = rowblk + m * 16 + quad * 4 + rr;
                Pout[(size_t)grow * 128 + col] = __float2half(acc2[m][rr]);
            }
        }
    }
}

// ---- Reduce: out[i][c] = 256*sum_k invd[i,k]*P[nbr[i,k]][k*16+c] + b2[c] ----
// 2-way split per node: thread (d, half) covers cols half*8..+8.  (r19 form.)
__global__ __launch_bounds__(256) void reduce_kernel(
    const __half* __restrict__ P, const __half* __restrict__ invd,
    const int* __restrict__ nbr, const float* __restrict__ b2,
    float* __restrict__ outp) {
    const int t = blockIdx.x * 256 + threadIdx.x;
    const int d = t >> 1;
    const int half = t & 1;

    const int4* nrow = (const int4*)(nbr + (size_t)d * 8);
    const int4 iA = nrow[0];
    const int4 iB = nrow[1];
    const int idx[8] = {iA.x, iA.y, iA.z, iA.w, iB.x, iB.y, iB.z, iB.w};
    const f16x8 iv = *(const f16x8*)(invd + (size_t)d * 8);

    // Issue all 8 gather loads up front.
    f16x8 v[8];
#pragma unroll
    for (int k = 0; k < 8; ++k)
        v[k] = *(const f16x8*)(P + (size_t)idx[k] * 128 + k * 16 + half * 8);

    float acc[8];
#pragma unroll
    for (int c = 0; c < 8; ++c) acc[c] = 0.f;
#pragma unroll
    for (int k = 0; k < 8; ++k) {
        const float w = (float)iv[k];
#pragma unroll
        for (int c = 0; c < 8; ++c) acc[c] += w * (float)v[k][c];
    }

    const float* bp = b2 + half * 8;
    float4 o[2];
#pragma unroll
    for (int q = 0; q < 2; ++q) {
        o[q].x = acc[q * 4 + 0] * 256.0f + bp[q * 4 + 0];
        o[q].y = acc[q * 4 + 1] * 256.0f + bp[q * 4 + 1];
        o[q].z = acc[q * 4 + 2] * 256.0f + bp[q * 4 + 2];
        o[q].w = acc[q * 4 + 3] * 256.0f + bp[q * 4 + 3];
    }
    float4* dst = (float4*)(outp + (size_t)d * 16 + half * 8);
    dst[0] = o[0];
    dst[1] = o[1];
}

extern "C" void kernel_launch(void* const* d_in, const int* in_sizes, int n_in,
                              void* d_out, int out_size, void* d_ws, size_t ws_size,
                              hipStream_t stream) {
    const float* h   = (const float*)d_in[0];
    const float* pos = (const float*)d_in[1];
    const int*   nbr = (const int*)d_in[2];
    const float* W0  = (const float*)d_in[3];
    const float* b0  = (const float*)d_in[4];
    const float* W1  = (const float*)d_in[5];
    const float* b1  = (const float*)d_in[6];
    const float* W2  = (const float*)d_in[7];
    const float* b2  = (const float*)d_in[8];

    const int N = NNODES;

    // ws: h1 (64 MiB) + P (64 MiB) = 128 MiB exactly.
    char* w = (char*)d_ws;
    __half* h1 = (__half*)w;                               // 67,108,864 B
    __half* P  = (__half*)(w + (size_t)67108864);          // 67,108,864 B
    __half* invd2 = (__half*)w;                            // 4 MiB, into dead h1

    // d_out doubles as scratch until reduce overwrites all of it (16 MiB).
    char* ob = (char*)d_out;
    __half* invd = (__half*)(ob + 0);                      // 4,194,304 B
    __half* W1f  = (__half*)(ob + 4194304);                // 262,144 B
    __half* Wf2s = (__half*)(ob + 4456448);                // 32,768 B (end 4,489,216)

    // layer0 (+fused W0 staging, invd compute, W1f/W2s shuffle tail blocks).
    layer0_kernel<<<2624, 256, 0, stream>>>(h, pos, nbr, W0, W1, W2, b0,
                                            invd, W1f, Wf2s, h1);
    layer1p_kernel<<<N / 64, 512, 0, stream>>>(h1, invd, nbr, W1f, Wf2s, b1, P);

    // h1 is dead now; move invd out of d_out before reduce writes d_out.
    (void)hipMemcpyAsync(invd2, invd, 4194304, hipMemcpyDeviceToDevice, stream);

    reduce_kernel<<<(N * 2) / 256, 256, 0, stream>>>(P, invd2, nbr, b2, (float*)d_out);
}

// Round 13
// 309.208 us; speedup vs baseline: 1.0338x; 1.0338x over previous
//
#include <hip/hip_runtime.h>
#include <hip/hip_fp16.h>

// 3-layer gather-GEMM GNN (N=262144, K=8, 16->128->128->16), f16 MFMA.
// Round 25: isolate the last untested knob in layer1p — BARRIER COUNT.
// The LDS-shared A-tile structure is bandwidth-forced (wave-private A => 8x
// B traffic or 8x A traffic; analyzed r24 post-mortem), so the only lever
// left inside it is rendezvous frequency. As becomes 2 buffers x 2
// neighbor-halves (64 KB): phase p computes nb={2p,2p+1} (32 MFMAs between
// barriers), stages pair p+1, barriers ONCE -> 4 barriers total (was 8),
// 2x gather cover per barrier. Buffer-reuse distance = 2 phases -> 2
// buffers suffice. MFMA accumulation order per acc element unchanged
// (nb 0..7, ks 0..3 ascending) -> bit-identical output.
// Everything else = r23 measured base (prep_all 640 blocks, layer0 with
// fused h-conversion + invd, reduce 2-way, r19 register discipline).
//
// Workspace: ws = h1 (64 MiB) + P (64 MiB) = 128 MiB exactly. invd/Wf live
// in d_out scratch; invd is d2d-copied into dead h1 before the reduce (which
// writes d_out).

typedef _Float16 f16x8 __attribute__((ext_vector_type(8)));
typedef float f32x4 __attribute__((ext_vector_type(4)));

#define NNODES 262144

// ---- Prep: weight shuffles only.
//      [0,64) W0 | [64,576) W1 | [576,640) W2s ----
__global__ __launch_bounds__(256) void prep_all_kernel(
    const float* __restrict__ W0, __half* __restrict__ W0f,
    const float* __restrict__ W1, __half* __restrict__ W1f,
    const float* __restrict__ W2, __half* __restrict__ W2f) {
    const int b = blockIdx.x;
    const int t = threadIdx.x;
    if (b < 64) {                        // W0 fragment shuffle: KT=128, FO=128
        int e = b * 256 + t;             // 16384 elems
        int j = e & 7;
        int lane = (e >> 3) & 63;
        int rest = e >> 9;
        int tt = rest % 8;
        int s = rest / 8;
        int k = s * 32 + (lane >> 4) * 8 + j;
        int n = tt * 16 + (lane & 15);
        W0f[e] = __float2half(W0[k * 128 + n]);
    } else if (b < 576) {                // W1 fragment shuffle: KT=1024, FO=128
        int e = (b - 64) * 256 + t;      // 131072 elems
        int j = e & 7;
        int lane = (e >> 3) & 63;
        int rest = e >> 9;
        int tt = rest % 8;
        int s = rest / 8;
        int k = s * 32 + (lane >> 4) * 8 + j;
        int n = tt * 16 + (lane & 15);
        W1f[e] = __float2half(W1[k * 128 + n]);
    } else {                             // W2 stacked shuffle: 16384 elems
        int e = (b - 576) * 256 + t;
        int j = e & 7;
        int lane = (e >> 3) & 63;
        int rest = e >> 9;
        int tt = rest % 8;
        int s = rest / 8;
        int k = s * 32 + (lane >> 4) * 8 + j;
        W2f[e] = __float2half(W2[(size_t)(tt * 128 + k) * 16 + (lane & 15)]);
    }
}

// ---------------- L0: F_IN=16, F_OUT=128, 128 rows/block ----------------
// Fuses: h f32->f16 conversion (in-register) + invd computation (from pos,
// stored to global for layer1p/reduce).  (r23 measured form.)
__global__ __launch_bounds__(256) void layer0_kernel(
    const float* __restrict__ h, const float* __restrict__ pos,
    const int* __restrict__ nbr, const __half* __restrict__ Wf,
    const float* __restrict__ bias, __half* __restrict__ invd,
    __half* __restrict__ outp) {
    __shared__ __align__(16) __half Bs[16384];  // 32 KB: weights, then h1-tile bounce

    const int tid = threadIdx.x;
    const int wave = tid >> 6;
    const int lane = tid & 63;
    const int quad = lane >> 4;
    const int lmod = lane & 15;
    const int mbase = blockIdx.x * 128 + wave * 16 + lmod;

    // Stage weights (independent of the gather chains below).
    {
        const uint4* src = (const uint4*)Wf;
        uint4* dst = (uint4*)Bs;
#pragma unroll
        for (int i = 0; i < 8; ++i) dst[i * 256 + tid] = src[i * 256 + tid];
    }

    int idx[2][8];
#pragma unroll
    for (int mt = 0; mt < 2; ++mt) {
        const int m = mbase + mt * 64;
        const int4* nrow = (const int4*)(nbr + (size_t)m * 8);
        const int4 iA = nrow[0];
        const int4 iB = nrow[1];
        idx[mt][0] = iA.x; idx[mt][1] = iA.y; idx[mt][2] = iA.z; idx[mt][3] = iA.w;
        idx[mt][4] = iB.x; idx[mt][5] = iB.y; idx[mt][6] = iB.z; idx[mt][7] = iB.w;
    }

    // invd in-kernel (fused prep_edges): identical f32 math as the old
    // prep pass -> bit-identical. 4x redundant across quads (L1-broadcast).
    f16x8 invr[2];
#pragma unroll
    for (int mt = 0; mt < 2; ++mt) {
        const int m = mbase + mt * 64;
        const float px = pos[m * 3 + 0];
        const float py = pos[m * 3 + 1];
        const float pz = pos[m * 3 + 2];
#pragma unroll
        for (int k = 0; k < 8; ++k) {
            const int n = idx[mt][k];
            const float dx = px - pos[n * 3 + 0];
            const float dy = py - pos[n * 3 + 1];
            const float dz = pz - pos[n * 3 + 2];
            float d = sqrtf(dx * dx + dy * dy + dz * dz);
            if (d == 0.0f) d = 0.5f;     // reference: where(dist==0, 0.5, dist)
            invr[mt][k] = (_Float16)((1.0f / d) * 0.00390625f);  // prescale 1/256
        }
        if (quad == 0) *(f16x8*)(invd + (size_t)m * 8) = invr[mt];
    }

    f32x4 acc[2][8];
#pragma unroll
    for (int mt = 0; mt < 2; ++mt)
#pragma unroll
        for (int t = 0; t < 8; ++t) acc[mt][t] = f32x4{0.f, 0.f, 0.f, 0.f};

    __syncthreads();

#pragma unroll
    for (int s = 0; s < 4; ++s) {
        const int nb = 2 * s + (quad >> 1);
        f16x8 as[2];
#pragma unroll
        for (int mt = 0; mt < 2; ++mt) {
            const float* hp = h + (size_t)idx[mt][nb] * 16 + (quad & 1) * 8;
            const float4 f0 = *(const float4*)(hp);
            const float4 f1 = *(const float4*)(hp + 4);
            f16x8 av;
            av[0] = (_Float16)f0.x; av[1] = (_Float16)f0.y;
            av[2] = (_Float16)f0.z; av[3] = (_Float16)f0.w;
            av[4] = (_Float16)f1.x; av[5] = (_Float16)f1.y;
            av[6] = (_Float16)f1.z; av[7] = (_Float16)f1.w;
            as[mt] = av * invr[mt][nb];
        }
#pragma unroll
        for (int t = 0; t < 8; ++t) {
            f16x8 b = *(const f16x8*)(Bs + ((size_t)(s * 8 + t) * 64 + lane) * 8);
#pragma unroll
            for (int mt = 0; mt < 2; ++mt)
                acc[mt][t] = __builtin_amdgcn_mfma_f32_16x16x32_f16(as[mt], b, acc[mt][t], 0, 0, 0);
        }
    }

    // ---- Epilogue: bounce 128x128 f16 tile through Bs, coalesced dump ----
    __syncthreads();  // all Bs (weights) reads complete before overwrite
#pragma unroll
    for (int mt = 0; mt < 2; ++mt) {
#pragma unroll
        for (int t = 0; t < 8; ++t) {
            const int col = t * 16 + lmod;
            const float bv = bias[col];
#pragma unroll
            for (int rr = 0; rr < 4; ++rr) {
                const int lrow = mt * 64 + wave * 16 + quad * 4 + rr;
                float v = acc[mt][t][rr] * 256.0f + bv;
                Bs[lrow * 128 + col] = __float2half(v);
            }
        }
    }
    __syncthreads();
    {
        const int lrow = tid >> 1;                 // 0..127
        const int cb = (tid & 1) * 64;             // col base 0 or 64
        __half* gdst = outp + (size_t)(blockIdx.x * 128 + lrow) * 128 + cb;
        const __half* lsrc = Bs + lrow * 128 + cb;
#pragma unroll
        for (int j = 0; j < 8; ++j)
            *(f16x8*)(gdst + j * 8) = *(const f16x8*)(lsrc + j * 8);
    }
}

// ------- L1+P: F_IN=128, F_OUT=128, 64 rows/block, fused P projection -------
// 512 threads / 8 waves; wave owns one col-tile t = wave.
// PAIRED staging: As[buf][k] holds neighbors {2p, 2p+1}; ONE barrier per
// pair (4 total, was 8). Buffer-reuse distance = 2 phases.
// LDS: seg-major + XOR swizzle, 16B granules: off16(seg,row) =
//   seg*64 + (row & ~15) + ((row ^ seg) & 15)   -> spans [0, 1024) granules.
__device__ __forceinline__ int off16(int seg, int row) {
    return seg * 64 + (row & ~15) + ((row ^ seg) & 15);
}

__global__ __launch_bounds__(512, 4) void layer1p_kernel(
    const __half* __restrict__ hprev, const __half* __restrict__ invd,
    const int* __restrict__ nbr, const __half* __restrict__ Wf,
    const __half* __restrict__ Wf2s, const float* __restrict__ bias,
    __half* __restrict__ Pout) {
    __shared__ __align__(16) __half As[2][2][8192];  // [buf][nb-half] = 64 KB

    const int tid = threadIdx.x;
    const int wave = tid >> 6;          // 0..7: this wave's col-tile
    const int lane = tid & 63;
    const int quad = lane >> 4;
    const int lmod = lane & 15;
    const int rowblk = blockIdx.x * 64;
    const int seg = lmod;               // staging: this thread's 16B segment

    // Staging rows: r0 = wave*4 + quad (0..31) and r0+32; seg = lmod.
    const int r0 = wave * 4 + quad;
    const int* nbp = nbr + (size_t)(rowblk + r0) * 8;      // +256 ints = row r0+32
    const __half* ivp = invd + (size_t)(rowblk + r0) * 8;  // +256 halves = row r0+32

    const int soff0 = off16(seg, r0) * 8;        // halves
    const int soff1 = off16(seg, r0 + 32) * 8;

    // Fragment-read offsets (halves): off16(ks*4+quad, m*16+lmod)*8 =
    // roff4[ks] + m*128.
    int roff4[4];
#pragma unroll
    for (int ks = 0; ks < 4; ++ks) {
        const int sg = ks * 4 + quad;
        roff4[ks] = (sg * 64 + ((lmod ^ sg) & 15)) * 8;
    }

    // This wave's B fragments: col-tile t = wave; k-step s at +s*4096 halves.
    const __half* WfB = Wf + ((size_t)wave * 64 + lane) * 8;

    // Half-width B ring over flat half-phase hp = nb*2 + h (0..15).
    f16x8 Bc[2], Bn[2];
#pragma unroll
    for (int ks2 = 0; ks2 < 2; ++ks2)
        Bc[ks2] = *(const f16x8*)(WfB + (size_t)ks2 * 4096);

    // Prologue: gather + stage pair 0 (nb 0,1) into As[0][0..1].
    f16x8 ga[2][2];  // [nb-in-pair][row 0/1]
    {
        const int i00 = nbp[0],   i01 = nbp[256];
        const int i10 = nbp[1],   i11 = nbp[257];
        ga[0][0] = *(const f16x8*)(hprev + (size_t)i00 * 128 + seg * 8);
        ga[0][1] = *(const f16x8*)(hprev + (size_t)i01 * 128 + seg * 8);
        ga[1][0] = *(const f16x8*)(hprev + (size_t)i10 * 128 + seg * 8);
        ga[1][1] = *(const f16x8*)(hprev + (size_t)i11 * 128 + seg * 8);
    }
    {
        const _Float16 s00 = *(const _Float16*)(ivp + 0);
        const _Float16 s01 = *(const _Float16*)(ivp + 256);
        const _Float16 s10 = *(const _Float16*)(ivp + 1);
        const _Float16 s11 = *(const _Float16*)(ivp + 257);
        *(f16x8*)(&As[0][0][soff0]) = ga[0][0] * s00;
        *(f16x8*)(&As[0][0][soff1]) = ga[0][1] * s01;
        *(f16x8*)(&As[0][1][soff0]) = ga[1][0] * s10;
        *(f16x8*)(&As[0][1][soff1]) = ga[1][1] * s11;
    }
    __syncthreads();

    f32x4 acc[4];
#pragma unroll
    for (int m = 0; m < 4; ++m) acc[m] = f32x4{0.f, 0.f, 0.f, 0.f};

#pragma unroll
    for (int p = 0; p < 4; ++p) {
        const int cur = p & 1;
        // Gather pair p+1 (nb 2p+2, 2p+3) — issued at phase start, consumed
        // at phase end: covered by this phase's 32 MFMAs.
        if (p < 3) {
            const int nb0 = 2 * p + 2, nb1 = 2 * p + 3;
            const int i00 = nbp[nb0], i01 = nbp[nb0 + 256];
            const int i10 = nbp[nb1], i11 = nbp[nb1 + 256];
            ga[0][0] = *(const f16x8*)(hprev + (size_t)i00 * 128 + seg * 8);
            ga[0][1] = *(const f16x8*)(hprev + (size_t)i01 * 128 + seg * 8);
            ga[1][0] = *(const f16x8*)(hprev + (size_t)i10 * 128 + seg * 8);
            ga[1][1] = *(const f16x8*)(hprev + (size_t)i11 * 128 + seg * 8);
        }
        // Compute nb = 2p, 2p+1 from As[cur][0], As[cur][1].
#pragma unroll
        for (int k = 0; k < 2; ++k) {
            const int nb = 2 * p + k;
            const __half* base = &As[cur][k][0];
#pragma unroll
            for (int h = 0; h < 2; ++h) {
                const int hp = nb * 2 + h;
                if (hp < 15) {
#pragma unroll
                    for (int ks2 = 0; ks2 < 2; ++ks2)
                        Bn[ks2] = *(const f16x8*)(WfB + (size_t)((hp + 1) * 2 + ks2) * 4096);
                }
#pragma unroll
                for (int m = 0; m < 4; ++m) {
#pragma unroll
                    for (int ks2 = 0; ks2 < 2; ++ks2) {
                        f16x8 a = *(const f16x8*)(base + roff4[h * 2 + ks2] + m * 128);
                        acc[m] = __builtin_amdgcn_mfma_f32_16x16x32_f16(a, Bc[ks2], acc[m], 0, 0, 0);
                    }
                }
                Bc[0] = Bn[0];
                Bc[1] = Bn[1];
            }
        }
        // Stage pair p+1 into As[cur^1], ONE barrier per pair.
        if (p < 3) {
            const int nb0 = 2 * p + 2, nb1 = 2 * p + 3;
            const _Float16 s00 = *(const _Float16*)(ivp + nb0);
            const _Float16 s01 = *(const _Float16*)(ivp + nb0 + 256);
            const _Float16 s10 = *(const _Float16*)(ivp + nb1);
            const _Float16 s11 = *(const _Float16*)(ivp + nb1 + 256);
            *(f16x8*)(&As[cur ^ 1][0][soff0]) = ga[0][0] * s00;
            *(f16x8*)(&As[cur ^ 1][0][soff1]) = ga[0][1] * s01;
            *(f16x8*)(&As[cur ^ 1][1][soff0]) = ga[1][0] * s10;
            *(f16x8*)(&As[cur ^ 1][1][soff1]) = ga[1][1] * s11;
            __syncthreads();
        }
    }

    // ---- Fused epilogue: h2 = leaky(acc*256 + b1) -> LDS (swizzled) ----
    // As[0] safe to overwrite: its last readers (pair 2, phase p=2) all
    // passed the barrier at end of p=2; phase 3 reads As[1] only.
    // h2 element (row,col) at granule off16(col>>3, row), half (col&7).
    // Wave writes its 16 cols: col = wave*16 + lmod.
    __half* As0 = &As[0][0][0];
    {
        const int col = wave * 16 + lmod;
        const float bv = bias[col];
        const int sg = col >> 3;
        const int jj = col & 7;
#pragma unroll
        for (int m = 0; m < 4; ++m) {
#pragma unroll
            for (int rr = 0; rr < 4; ++rr) {
                const int row = m * 16 + quad * 4 + rr;
                float v = acc[m][rr] * 256.0f + bv;
                v = (v >= 0.f) ? v : 0.01f * v;
                As0[off16(sg, row) * 8 + jj] = __float2half(v);
            }
        }
    }
    __syncthreads();

    // ---- P = h2 @ W2s (K=128, 4 k-steps); wave owns col-tile wave ----
    const __half* WfB2 = Wf2s + ((size_t)wave * 64 + lane) * 8;
    f16x8 B2[4];
#pragma unroll
    for (int ks = 0; ks < 4; ++ks)
        B2[ks] = *(const f16x8*)(WfB2 + (size_t)ks * 4096);

    f32x4 acc2[4];
#pragma unroll
    for (int m = 0; m < 4; ++m) acc2[m] = f32x4{0.f, 0.f, 0.f, 0.f};
#pragma unroll
    for (int m = 0; m < 4; ++m) {
#pragma unroll
        for (int ks = 0; ks < 4; ++ks) {
            f16x8 a2 = *(const f16x8*)(&As0[roff4[ks] + m * 128]);
            acc2[m] = __builtin_amdgcn_mfma_f32_16x16x32_f16(a2, B2[ks], acc2[m], 0, 0, 0);
        }
    }

    // ---- write P (fp16, true scale) ----
    {
        const int col = wave * 16 + lmod;
#pragma unroll
        for (int m = 0; m < 4; ++m) {
#pragma unroll
            for (int rr = 0; rr < 4; ++rr) {
                const int grow = rowblk + m * 16 + quad * 4 + rr;
                Pout[(size_t)grow * 128 + col] = __float2half(acc2[m][rr]);
            }
        }
    }
}

// ---- Reduce: out[i][c] = 256*sum_k invd[i,k]*P[nbr[i,k]][k*16+c] + b2[c] ----
// 2-way split per node: thread (d, half) covers cols half*8..+8.  (r19 form.)
__global__ __launch_bounds__(256) void reduce_kernel(
    const __half* __restrict__ P, const __half* __restrict__ invd,
    const int* __restrict__ nbr, const float* __restrict__ b2,
    float* __restrict__ outp) {
    const int t = blockIdx.x * 256 + threadIdx.x;
    const int d = t >> 1;
    const int half = t & 1;

    const int4* nrow = (const int4*)(nbr + (size_t)d * 8);
    const int4 iA = nrow[0];
    const int4 iB = nrow[1];
    const int idx[8] = {iA.x, iA.y, iA.z, iA.w, iB.x, iB.y, iB.z, iB.w};
    const f16x8 iv = *(const f16x8*)(invd + (size_t)d * 8);

    // Issue all 8 gather loads up front.
    f16x8 v[8];
#pragma unroll
    for (int k = 0; k < 8; ++k)
        v[k] = *(const f16x8*)(P + (size_t)idx[k] * 128 + k * 16 + half * 8);

    float acc[8];
#pragma unroll
    for (int c = 0; c < 8; ++c) acc[c] = 0.f;
#pragma unroll
    for (int k = 0; k < 8; ++k) {
        const float w = (float)iv[k];
#pragma unroll
        for (int c = 0; c < 8; ++c) acc[c] += w * (float)v[k][c];
    }

    const float* bp = b2 + half * 8;
    float4 o[2];
#pragma unroll
    for (int q = 0; q < 2; ++q) {
        o[q].x = acc[q * 4 + 0] * 256.0f + bp[q * 4 + 0];
        o[q].y = acc[q * 4 + 1] * 256.0f + bp[q * 4 + 1];
        o[q].z = acc[q * 4 + 2] * 256.0f + bp[q * 4 + 2];
        o[q].w = acc[q * 4 + 3] * 256.0f + bp[q * 4 + 3];
    }
    float4* dst = (float4*)(outp + (size_t)d * 16 + half * 8);
    dst[0] = o[0];
    dst[1] = o[1];
}

extern "C" void kernel_launch(void* const* d_in, const int* in_sizes, int n_in,
                              void* d_out, int out_size, void* d_ws, size_t ws_size,
                              hipStream_t stream) {
    const float* h   = (const float*)d_in[0];
    const float* pos = (const float*)d_in[1];
    const int*   nbr = (const int*)d_in[2];
    const float* W0  = (const float*)d_in[3];
    const float* b0  = (const float*)d_in[4];
    const float* W1  = (const float*)d_in[5];
    const float* b1  = (const float*)d_in[6];
    const float* W2  = (const float*)d_in[7];
    const float* b2  = (const float*)d_in[8];

    const int N = NNODES;

    // ws: h1 (64 MiB) + P (64 MiB) = 128 MiB exactly.
    char* w = (char*)d_ws;
    __half* h1 = (__half*)w;                               // 67,108,864 B
    __half* P  = (__half*)(w + (size_t)67108864);          // 67,108,864 B
    __half* invd2 = (__half*)w;                            // 4 MiB, into dead h1

    // d_out doubles as scratch until reduce overwrites all of it (16 MiB).
    char* ob = (char*)d_out;
    __half* invd = (__half*)(ob + 0);                      // 4,194,304 B
    __half* W0f  = (__half*)(ob + 4194304);                // 32,768 B
    __half* W1f  = (__half*)(ob + 4227072);                // 262,144 B
    __half* Wf2s = (__half*)(ob + 4489216);                // 32,768 B (end 4,521,984)

    // Prep: weight shuffles only (64 + 512 + 64 = 640 blocks).
    prep_all_kernel<<<640, 256, 0, stream>>>(W0, W0f, W1, W1f, W2, Wf2s);

    // layer0 fuses h-conversion + invd computation (writes invd).
    layer0_kernel<<<N / 128, 256, 0, stream>>>(h, pos, nbr, W0f, b0, invd, h1);
    layer1p_kernel<<<N / 64, 512, 0, stream>>>(h1, invd, nbr, W1f, Wf2s, b1, P);

    // h1 is dead now; move invd out of d_out before reduce writes d_out.
    (void)hipMemcpyAsync(invd2, invd, 4194304, hipMemcpyDeviceToDevice, stream);

    reduce_kernel<<<(N * 2) / 256, 256, 0, stream>>>(P, invd2, nbr, b2, (float*)d_out);
}